// Round 9
// baseline (2757.789 us; speedup 1.0000x reference)
//
#include <hip/hip_runtime.h>
#include <cstdint>
#include <cstddef>

// Problem constants
#define T_SEQ 512
#define BATCH 128
#define HID   128
#define G4    512      // 4*H
#define NCLS  10

typedef unsigned short u16;
typedef unsigned int   u32;
typedef short bf16x8 __attribute__((ext_vector_type(8)));   // 8 bf16 = 4 VGPR
typedef float f32x4  __attribute__((ext_vector_type(4)));   // MFMA acc

__device__ __forceinline__ float sigmoidf_(float x) {
    return 1.f / (1.f + __expf(-x));
}
__device__ __forceinline__ float tanhf_(float x) {
    return 2.f / (1.f + __expf(-2.f * x)) - 1.f;
}

__device__ __forceinline__ u16 bf16rne(float f) {
    u32 u = __float_as_uint(f);
    u32 r = (u + 0x7fffu + ((u >> 16) & 1u)) >> 16;
    return (u16)r;
}
__device__ __forceinline__ float bf16tof(u16 s) {
    return __uint_as_float(((u32)s) << 16);
}
__device__ __forceinline__ uint4 pack8(const u16* h) {
    uint4 u;
    u.x = (u32)h[0] | ((u32)h[1] << 16);
    u.y = (u32)h[2] | ((u32)h[3] << 16);
    u.z = (u32)h[4] | ((u32)h[5] << 16);
    u.w = (u32)h[6] | ((u32)h[7] << 16);
    return u;
}

// ---------------------------------------------------------------------------
// prep_w: split weight matrices into bf16 hi/lo pairs.
//   - wih l0f/l0r: [512][300] -> K-padded [512][320]
//   - wih l1f:     [512][256]
//   - whh l0f/l0r/l1f: [512][128]  (NEW: for the MFMA recurrence)
// ---------------------------------------------------------------------------
__global__ __launch_bounds__(256)
void prep_w(const float* __restrict__ w0f, const float* __restrict__ w0r,
            const float* __restrict__ w1f,
            const float* __restrict__ hh0f, const float* __restrict__ hh0r,
            const float* __restrict__ hh1f,
            u16* __restrict__ W0f1, u16* __restrict__ W0f2,
            u16* __restrict__ W0r1, u16* __restrict__ W0r2,
            u16* __restrict__ W1f1, u16* __restrict__ W1f2,
            u16* __restrict__ H0f1, u16* __restrict__ H0f2,
            u16* __restrict__ H0r1, u16* __restrict__ H0r2,
            u16* __restrict__ H1f1, u16* __restrict__ H1f2)
{
    int idx = blockIdx.x * 256 + threadIdx.x;
    if (idx < 512 * 320) {
        int r = idx / 320, k = idx - r * 320;
        float v = (k < 300) ? w0f[r * 300 + k] : 0.f;
        u16 a = bf16rne(v);
        W0f1[idx] = a; W0f2[idx] = bf16rne(v - bf16tof(a));
        v = (k < 300) ? w0r[r * 300 + k] : 0.f;
        a = bf16rne(v);
        W0r1[idx] = a; W0r2[idx] = bf16rne(v - bf16tof(a));
    }
    if (idx < 512 * 256) {
        float v = w1f[idx];
        u16 a = bf16rne(v);
        W1f1[idx] = a; W1f2[idx] = bf16rne(v - bf16tof(a));
    }
    if (idx < 512 * 128) {
        float v = hh0f[idx];
        u16 a = bf16rne(v);
        H0f1[idx] = a; H0f2[idx] = bf16rne(v - bf16tof(a));
        v = hh0r[idx];
        a = bf16rne(v);
        H0r1[idx] = a; H0r2[idx] = bf16rne(v - bf16tof(a));
        v = hh1f[idx];
        a = bf16rne(v);
        H1f1[idx] = a; H1f2[idx] = bf16rne(v - bf16tof(a));
    }
}

// ---------------------------------------------------------------------------
// Split-bf16 MFMA GEMM (unchanged from round 7; measured absmax 7.6e-6).
// ---------------------------------------------------------------------------
__global__ __launch_bounds__(256)
void gemm_mfma(const float* __restrict__ A, const int* __restrict__ rows,
               int lda, int Kp,
               const u16* __restrict__ W1, const u16* __restrict__ W2,
               const float* __restrict__ bih, const float* __restrict__ bhh,
               float* __restrict__ out, int tcshift, int tc0)
{
    __shared__ __align__(16) u16 lA1[128][40];
    __shared__ __align__(16) u16 lA2[128][40];
    __shared__ __align__(16) u16 lW1[128][40];
    __shared__ __align__(16) u16 lW2[128][40];

    const int tid = threadIdx.x;
    const int tn = blockIdx.x & 3;
    const int tm = blockIdx.x >> 2;
    const int m0 = tm * 128, n0 = tn * 128;

    const int wave = tid >> 6, lane = tid & 63;
    const int wm = wave & 1, wn = wave >> 1;
    const int quad = lane >> 4, l16 = lane & 15;

    const int srow = tid >> 1;
    const int sk   = (tid & 1) * 16;

    const float* arow;
    {
        int m  = m0 + srow;
        int b  = m >> tcshift;
        int tt = m & ((1 << tcshift) - 1);
        int grow = b * T_SEQ + tc0 + tt;
        int r = rows ? rows[grow] : grow;
        arow = A + (size_t)r * lda;
    }
    const u16* w1row = W1 + (size_t)(n0 + srow) * Kp + sk;
    const u16* w2row = W2 + (size_t)(n0 + srow) * Kp + sk;

    f32x4 acc[4][4];
#pragma unroll
    for (int i = 0; i < 4; i++)
#pragma unroll
        for (int j = 0; j < 4; j++) acc[i][j] = f32x4{0.f, 0.f, 0.f, 0.f};

    for (int k0 = 0; k0 < Kp; k0 += 32) {
        float av[16];
#pragma unroll
        for (int v = 0; v < 4; v++) {
            int k = k0 + sk + v * 4;
            float4 t = {0.f, 0.f, 0.f, 0.f};
            if (k + 4 <= lda) t = *(const float4*)(arow + k);
            av[v * 4 + 0] = t.x; av[v * 4 + 1] = t.y;
            av[v * 4 + 2] = t.z; av[v * 4 + 3] = t.w;
        }
        uint4 wv1a = *(const uint4*)(w1row + k0);
        uint4 wv1b = *(const uint4*)(w1row + k0 + 8);
        uint4 wv2a = *(const uint4*)(w2row + k0);
        uint4 wv2b = *(const uint4*)(w2row + k0 + 8);

        u16 h1[16], h2[16];
#pragma unroll
        for (int j = 0; j < 16; j++) {
            u16 a = bf16rne(av[j]);
            h1[j] = a;
            h2[j] = bf16rne(av[j] - bf16tof(a));
        }

        __syncthreads();
        *(uint4*)&lA1[srow][sk]     = pack8(h1);
        *(uint4*)&lA1[srow][sk + 8] = pack8(h1 + 8);
        *(uint4*)&lA2[srow][sk]     = pack8(h2);
        *(uint4*)&lA2[srow][sk + 8] = pack8(h2 + 8);
        *(uint4*)&lW1[srow][sk]     = wv1a;
        *(uint4*)&lW1[srow][sk + 8] = wv1b;
        *(uint4*)&lW2[srow][sk]     = wv2a;
        *(uint4*)&lW2[srow][sk + 8] = wv2b;
        __syncthreads();

        bf16x8 fa1[4], fa2[4], fw1[4], fw2[4];
#pragma unroll
        for (int t = 0; t < 4; t++) {
            int ar = wm * 64 + t * 16 + l16;
            int wr = wn * 64 + t * 16 + l16;
            fa1[t] = *(const bf16x8*)&lA1[ar][quad * 8];
            fa2[t] = *(const bf16x8*)&lA2[ar][quad * 8];
            fw1[t] = *(const bf16x8*)&lW1[wr][quad * 8];
            fw2[t] = *(const bf16x8*)&lW2[wr][quad * 8];
        }

#pragma unroll
        for (int mt = 0; mt < 4; mt++)
#pragma unroll
            for (int nt = 0; nt < 4; nt++)
                acc[mt][nt] = __builtin_amdgcn_mfma_f32_16x16x32_bf16(
                    fa1[mt], fw1[nt], acc[mt][nt], 0, 0, 0);
#pragma unroll
        for (int mt = 0; mt < 4; mt++)
#pragma unroll
            for (int nt = 0; nt < 4; nt++)
                acc[mt][nt] = __builtin_amdgcn_mfma_f32_16x16x32_bf16(
                    fa1[mt], fw2[nt], acc[mt][nt], 0, 0, 0);
#pragma unroll
        for (int mt = 0; mt < 4; mt++)
#pragma unroll
            for (int nt = 0; nt < 4; nt++)
                acc[mt][nt] = __builtin_amdgcn_mfma_f32_16x16x32_bf16(
                    fa2[mt], fw1[nt], acc[mt][nt], 0, 0, 0);
    }

#pragma unroll
    for (int nt = 0; nt < 4; nt++) {
        int n = n0 + wn * 64 + nt * 16 + l16;
        float bv = bih[n] + bhh[n];
#pragma unroll
        for (int mt = 0; mt < 4; mt++) {
            int mb = m0 + wm * 64 + mt * 16 + quad * 4;
#pragma unroll
            for (int r = 0; r < 4; r++)
                out[(size_t)(mb + r) * G4 + n] = acc[mt][nt][r] + bv;
        }
    }
}

// ---------------------------------------------------------------------------
// MFMA LSTM recurrence. One WG (512 thr = 8 waves) per (dir, 16-batch tile).
// gates[16 batches][512] = h[16][128] @ whh^T via 16x16x32 bf16 MFMA with the
// PROVEN 3-pass split (h1·W1 + h1·W2 + h2·W1; same arithmetic as gemm_mfma).
//
// Why MFMA: both measured walls of the VALU recurrence disappear —
//  (a) h-sharing happens inside the matrix unit: LDS traffic 128 B/thread/step
//      (bf16 hi/lo fragments) vs 512 B (round-5 wall);
//  (b) weights live in B-fragments (32 bf16x8 = 128 VGPRs); even if the
//      allocator demotes them, the L2 stream is 256 KB per 16-batch step
//      (16 KB/batch vs 256 KB/batch in rounds 4/7), hidden under ~1600 cyc
//      of MFMA.
// Wave w owns N-tiles {w, w+8, w+16, w+24}: all 4 gates of unit
// u = w*16+l16 land on ONE lane -> no shuffles, no LDS gate array; c in
// registers (batches m = quad*4+r); h split double-buffered in LDS -> one
// barrier/step. xg loaded at step start, consumed after the MFMA block.
// MODE 0: grid 16 (dir = wg>>3), writes h0cat. MODE 1: grid 8, state only.
// ---------------------------------------------------------------------------
template <int MODE>
__global__ __launch_bounds__(512, 2)
void lstm_rec(const float* __restrict__ xg0, const float* __restrict__ xg1,
              const u16* __restrict__ Wh1f, const u16* __restrict__ Wh2f,
              const u16* __restrict__ Wh1r, const u16* __restrict__ Wh2r,
              float* __restrict__ hout,
              float* __restrict__ hst_f, float* __restrict__ cst_f,
              float* __restrict__ hst_r, float* __restrict__ cst_r,
              int Tc, int tc0f, int tc0r, int first)
{
    const int wg  = blockIdx.x;
    const int dir = (MODE == 0) ? (wg >> 3) : 0;
    const int bt  = wg & 7;
    const int b0  = bt * 16;
    const float* xgb = dir ? xg1 : xg0;
    const u16* Wh1 = dir ? Wh1r : Wh1f;
    const u16* Wh2 = dir ? Wh2r : Wh2f;
    float* hst = dir ? hst_r : hst_f;
    float* cst = dir ? cst_r : cst_f;
    const int tc0 = dir ? tc0r : tc0f;

    const int tid  = threadIdx.x;
    const int wave = tid >> 6;
    const int lane = tid & 63;
    const int quad = lane >> 4;
    const int l16  = lane & 15;
    const int ut   = wave * 16 + l16;     // unit this thread finalizes

    // B-fragments: gate g's tile at n = g*128 + ut; B[n][k=kc*32+quad*8+j]
    bf16x8 fw1[4][4], fw2[4][4];
#pragma unroll
    for (int g = 0; g < 4; g++) {
        const u16* p1 = Wh1 + (size_t)(g * 128 + ut) * 128 + quad * 8;
        const u16* p2 = Wh2 + (size_t)(g * 128 + ut) * 128 + quad * 8;
#pragma unroll
        for (int kc = 0; kc < 4; kc++) {
            fw1[g][kc] = *(const bf16x8*)(p1 + kc * 32);
            fw2[g][kc] = *(const bf16x8*)(p2 + kc * 32);
        }
    }
    asm volatile("" ::: "memory");

    __shared__ u16 h1_s[2][16][136];   // h hi (bf16), row-padded
    __shared__ u16 h2_s[2][16][136];   // h residual (bf16)

    // init h (split) and c
#pragma unroll
    for (int i = 0; i < 4; i++) {
        int e = tid + 512 * i;          // 0..2047 = 16 m x 128 u
        int m = e >> 7, u = e & 127;
        float hv = first ? 0.f : hst[(size_t)(b0 + m) * HID + u];
        u16 hi = bf16rne(hv);
        h1_s[0][m][u] = hi;
        h2_s[0][m][u] = bf16rne(hv - bf16tof(hi));
    }
    float c[4], hl[4];
#pragma unroll
    for (int r = 0; r < 4; r++) {
        c[r]  = first ? 0.f : cst[(size_t)(b0 + quad * 4 + r) * HID + ut];
        hl[r] = 0.f;
    }
    __syncthreads();

    const float* xp[4];
#pragma unroll
    for (int r = 0; r < 4; r++)
        xp[r] = xgb + (size_t)(b0 + quad * 4 + r) * Tc * G4 + ut;

    int buf = 0;
    for (int s = 0; s < Tc; s++) {
        const int tt = dir ? (Tc - 1 - s) : s;

        // xg for this step (16 loads; latency hidden under the MFMA block)
        float xv[4][4];
#pragma unroll
        for (int g = 0; g < 4; g++)
#pragma unroll
            for (int r = 0; r < 4; r++)
                xv[g][r] = xp[r][(size_t)tt * G4 + g * 128];

        // A-fragments: A[m=l16][k=kc*32+quad*8+j]
        bf16x8 fa1[4], fa2[4];
#pragma unroll
        for (int kc = 0; kc < 4; kc++) {
            fa1[kc] = *(const bf16x8*)&h1_s[buf][l16][kc * 32 + quad * 8];
            fa2[kc] = *(const bf16x8*)&h2_s[buf][l16][kc * 32 + quad * 8];
        }

        f32x4 acc[4];
#pragma unroll
        for (int g = 0; g < 4; g++) acc[g] = f32x4{0.f, 0.f, 0.f, 0.f};

        // 3-pass split, 4 independent chains (one per gate tile)
#pragma unroll
        for (int kc = 0; kc < 4; kc++)
#pragma unroll
            for (int g = 0; g < 4; g++)
                acc[g] = __builtin_amdgcn_mfma_f32_16x16x32_bf16(
                    fa1[kc], fw1[g][kc], acc[g], 0, 0, 0);
#pragma unroll
        for (int kc = 0; kc < 4; kc++)
#pragma unroll
            for (int g = 0; g < 4; g++)
                acc[g] = __builtin_amdgcn_mfma_f32_16x16x32_bf16(
                    fa1[kc], fw2[g][kc], acc[g], 0, 0, 0);
#pragma unroll
        for (int kc = 0; kc < 4; kc++)
#pragma unroll
            for (int g = 0; g < 4; g++)
                acc[g] = __builtin_amdgcn_mfma_f32_16x16x32_bf16(
                    fa2[kc], fw1[g][kc], acc[g], 0, 0, 0);

        // epilogue: unit ut, batches m = quad*4 + r; no cross-lane traffic
#pragma unroll
        for (int r = 0; r < 4; r++) {
            float ai = acc[0][r] + xv[0][r];
            float af = acc[1][r] + xv[1][r];
            float ag = acc[2][r] + xv[2][r];
            float ao = acc[3][r] + xv[3][r];
            float vi = sigmoidf_(ai);
            float vf = sigmoidf_(af);
            float vg = tanhf_(ag);
            float vo = sigmoidf_(ao);
            c[r] = vf * c[r] + vi * vg;
            float th = tanhf_(c[r]);
            float hv = vo * th;
            hl[r] = hv;
            int m = quad * 4 + r;
            u16 hi = bf16rne(hv);
            h1_s[buf ^ 1][m][ut] = hi;
            h2_s[buf ^ 1][m][ut] = bf16rne(hv - bf16tof(hi));
            if (MODE == 0)
                hout[((size_t)(b0 + m) * T_SEQ + (tc0 + tt)) * 256
                     + dir * HID + ut] = hv;
        }
        __syncthreads();
        buf ^= 1;
    }

#pragma unroll
    for (int r = 0; r < 4; r++) {
        hst[(size_t)(b0 + quad * 4 + r) * HID + ut] = hl[r];
        cst[(size_t)(b0 + quad * 4 + r) * HID + ut] = c[r];
    }
}

// ---------------------------------------------------------------------------
// Finale: layer-1 reverse LSTM's t=T-1 output is a SINGLE step from zero
// state (reverse scan processes t=T-1 first), then the FC head.
// ---------------------------------------------------------------------------
__global__ __launch_bounds__(512)
void final_k(const float* __restrict__ h0cat,
             const float* __restrict__ w_ih_r,
             const float* __restrict__ bih_r, const float* __restrict__ bhh_r,
             const float* __restrict__ h1f_last,
             const float* __restrict__ fc_w,
             const float* __restrict__ fc_b,
             float* __restrict__ out)
{
    int b = blockIdx.x;
    int j = threadIdx.x;  // 0..511
    __shared__ __align__(16) float hin[256];
    __shared__ __align__(16) float g_s[G4];
    __shared__ __align__(16) float hcat[256];

    if (j < 256) hin[j] = h0cat[((size_t)b * T_SEQ + (T_SEQ - 1)) * 256 + j];
    __syncthreads();

    float acc = bih_r[j] + bhh_r[j];
    const float* wr = w_ih_r + (size_t)j * 256;
#pragma unroll 8
    for (int k = 0; k < 256; k += 4) {
        float4 h4 = *(const float4*)&hin[k];
        float4 w4 = *(const float4*)&wr[k];
        acc += w4.x * h4.x + w4.y * h4.y + w4.z * h4.z + w4.w * h4.w;
    }
    float v = (j >= 256 && j < 384) ? tanhf_(acc) : sigmoidf_(acc);
    g_s[j] = v;
    if (j < 128) hcat[j] = h1f_last[(size_t)b * HID + j];
    __syncthreads();

    if (j < 128) {
        float gi = g_s[j], gg = g_s[j + 256], go = g_s[j + 384];
        float c = gi * gg;  // f * c0 with c0 = 0
        hcat[128 + j] = go * tanhf_(c);
    }
    __syncthreads();

    if (j < NCLS) {
        float a = fc_b[j];
        const float* fw = fc_w + (size_t)j * 256;
        for (int k = 0; k < 256; k++) a += fw[k] * hcat[k];
        out[(size_t)b * NCLS + j] = a;
    }
}

// ---------------------------------------------------------------------------
// Workspace:
//   [0, 64Mi)            h0cat [B][T][256]                        67,108,864
//   [64Mi, +384Ki)       6 state slots (h,c) x {l0f,l0r,l1f}         393,216
//   [.., +2,621,440)     bf16 splits: wih l0f/l0r [512][320]x2,
//                        wih l1f [512][256]x2, whh x3 [512][128]x2
//   [base, +2*chunk)     xgc0, xgc1 [B][Tc][512] fp32        262,144*Tc each
// Tc = largest power of two (<=256) fitting ws_size.
// ---------------------------------------------------------------------------
extern "C" void kernel_launch(void* const* d_in, const int* in_sizes, int n_in,
                              void* d_out, int out_size, void* d_ws, size_t ws_size,
                              hipStream_t stream)
{
    (void)in_sizes; (void)n_in; (void)out_size;

    const int*   x       = (const int*)  d_in[0];
    const float* emb     = (const float*)d_in[1];
    const float* wih_l0f = (const float*)d_in[2];
    const float* whh_l0f = (const float*)d_in[3];
    const float* bih_l0f = (const float*)d_in[4];
    const float* bhh_l0f = (const float*)d_in[5];
    const float* wih_l0r = (const float*)d_in[6];
    const float* whh_l0r = (const float*)d_in[7];
    const float* bih_l0r = (const float*)d_in[8];
    const float* bhh_l0r = (const float*)d_in[9];
    const float* wih_l1f = (const float*)d_in[10];
    const float* whh_l1f = (const float*)d_in[11];
    const float* bih_l1f = (const float*)d_in[12];
    const float* bhh_l1f = (const float*)d_in[13];
    const float* wih_l1r = (const float*)d_in[14];
    const float* whh_l1r = (const float*)d_in[15];  // unused (single step, h0=c0=0)
    const float* bih_l1r = (const float*)d_in[16];
    const float* bhh_l1r = (const float*)d_in[17];
    const float* fc_w    = (const float*)d_in[18];
    const float* fc_b    = (const float*)d_in[19];
    float* out = (float*)d_out;
    (void)whh_l1r;

    char* ws = (char*)d_ws;
    float* h0cat = (float*)ws;
    float* st    = (float*)(ws + (size_t)67108864);
    float* hst0 = st + 0 * 16384;
    float* cst0 = st + 1 * 16384;
    float* hst1 = st + 2 * 16384;
    float* cst1 = st + 3 * 16384;
    float* hst2 = st + 4 * 16384;
    float* cst2 = st + 5 * 16384;

    u16* wsp = (u16*)(ws + (size_t)67108864 + 393216);
    u16* W0f1 = wsp;                 // 163840 each (512x320)
    u16* W0f2 = wsp + 163840;
    u16* W0r1 = wsp + 327680;
    u16* W0r2 = wsp + 491520;
    u16* W1f1 = wsp + 655360;        // 131072 each (512x256)
    u16* W1f2 = wsp + 786432;
    u16* H0f1 = wsp + 917504;        // 65536 each (512x128)
    u16* H0f2 = wsp + 983040;
    u16* H0r1 = wsp + 1048576;
    u16* H0r2 = wsp + 1114112;
    u16* H1f1 = wsp + 1179648;
    u16* H1f2 = wsp + 1245184;

    const size_t base = (size_t)67108864 + 393216 + 2621440;

    int Tc = 256;
    while (Tc > 32 && base + 2 * (size_t)262144 * Tc > ws_size) Tc >>= 1;
    const int NC = T_SEQ / Tc;
    int tcshift = 0;
    while ((1 << tcshift) < Tc) tcshift++;
    float* xgc0 = (float*)(ws + base);
    float* xgc1 = xgc0 + (size_t)BATCH * Tc * G4;

    const dim3 gemm_grid(Tc * 4);  // (128*Tc/128) M-tiles x 4 N-tiles

    // Weight splits (once per launch)
    prep_w<<<dim3(640), 256, 0, stream>>>(
        wih_l0f, wih_l0r, wih_l1f, whh_l0f, whh_l0r, whh_l1f,
        W0f1, W0f2, W0r1, W0r2, W1f1, W1f2,
        H0f1, H0f2, H0r1, H0r2, H1f1, H1f2);

    // Phase 1: layer-0 fwd+rev fused (fwd chunks ascend, rev chunks descend)
    for (int i = 0; i < NC; i++) {
        int cf = i, cr = NC - 1 - i;
        gemm_mfma<<<gemm_grid, 256, 0, stream>>>(
            emb, x, 300, 320, W0f1, W0f2, bih_l0f, bhh_l0f,
            xgc0, tcshift, cf * Tc);
        gemm_mfma<<<gemm_grid, 256, 0, stream>>>(
            emb, x, 300, 320, W0r1, W0r2, bih_l0r, bhh_l0r,
            xgc1, tcshift, cr * Tc);
        lstm_rec<0><<<dim3(16), 512, 0, stream>>>(
            xgc0, xgc1, H0f1, H0f2, H0r1, H0r2, h0cat,
            hst0, cst0, hst1, cst1, Tc, cf * Tc, cr * Tc, i == 0);
    }

    // Phase 2: layer-1 forward (state only)
    for (int i = 0; i < NC; i++) {
        gemm_mfma<<<gemm_grid, 256, 0, stream>>>(
            h0cat, nullptr, 256, 256, W1f1, W1f2, bih_l1f, bhh_l1f,
            xgc0, tcshift, i * Tc);
        lstm_rec<1><<<dim3(8), 512, 0, stream>>>(
            xgc0, nullptr, H1f1, H1f2, nullptr, nullptr, nullptr,
            hst2, cst2, nullptr, nullptr, Tc, i * Tc, 0, i == 0);
    }

    // Phase 3: layer-1 reverse single step + FC head
    final_k<<<dim3(BATCH), 512, 0, stream>>>(
        h0cat, wih_l1r, bih_l1r, bhh_l1r, hst2, fc_w, fc_b, out);
}